// Round 1
// baseline (2029.798 us; speedup 1.0000x reference)
//
#include <hip/hip_runtime.h>

#define N_NODES 100000
#define N_EDGES 1600000
#define DIN 24
#define DH 64
#define DOUT 12
#define NEG_SLOPE 0.01f

// consts[0..3] = {c1_l1, c0_l1, c1_l2, c0_l2} where edge_term = e_w*c1 + c0
__global__ void k_consts(const float* __restrict__ emb_e_W, const float* __restrict__ emb_e_b,
                         const float* __restrict__ attn1, const float* __restrict__ attn2,
                         float* __restrict__ consts) {
    int lane = threadIdx.x; // 64 threads = 1 wave
    float w = emb_e_W[lane];
    float b = emb_e_b[lane];
    float a1 = attn1[2 * DH + lane];
    float a2 = attn2[2 * DH + lane];
    float c11 = w * a1, c01 = b * a1, c12 = w * a2, c02 = b * a2;
    for (int off = 32; off; off >>= 1) {
        c11 += __shfl_down(c11, off);
        c01 += __shfl_down(c01, off);
        c12 += __shfl_down(c12, off);
        c02 += __shfl_down(c02, off);
    }
    if (lane == 0) {
        consts[0] = c11; consts[1] = c01; consts[2] = c12; consts[3] = c02;
    }
}

// h[n][o] = feats[n,:] . emb_h_W[o,:] + b[o]
__global__ void k_embed(const float* __restrict__ feats, const float* __restrict__ W,
                        const float* __restrict__ b, float* __restrict__ h) {
    int idx = blockIdx.x * blockDim.x + threadIdx.x;
    if (idx >= N_NODES * DH) return;
    int n = idx >> 6, o = idx & 63;
    const float* f = feats + n * DIN;
    const float* w = W + o * DIN;
    float acc = b[o];
#pragma unroll
    for (int k = 0; k < DIN; ++k) acc += f[k] * w[k];
    h[idx] = acc;
}

// z = h @ Wfunc^T, hs = h @ Wself^T, s_src = z.a_src, s_dst = z.a_dst
// one 64-lane wave per node (lane = output channel o)
__global__ void k_node(const float* __restrict__ h,
                       const float* __restrict__ Wself, const float* __restrict__ Wfunc,
                       const float* __restrict__ attn,
                       float* __restrict__ z, float* __restrict__ hs,
                       float* __restrict__ s_src, float* __restrict__ s_dst) {
    int idx = blockIdx.x * blockDim.x + threadIdx.x;
    if (idx >= N_NODES * DH) return;
    int n = idx >> 6, o = idx & 63;
    const float4* hrow = (const float4*)(h + n * DH);
    const float4* ws = (const float4*)(Wself + o * DH);
    const float4* wf = (const float4*)(Wfunc + o * DH);
    float accs = 0.f, accf = 0.f;
#pragma unroll
    for (int k = 0; k < DH / 4; ++k) {
        float4 hv = hrow[k];
        float4 a = ws[k];
        float4 bq = wf[k];
        accs += hv.x * a.x + hv.y * a.y + hv.z * a.z + hv.w * a.w;
        accf += hv.x * bq.x + hv.y * bq.y + hv.z * bq.z + hv.w * bq.w;
    }
    z[idx] = accf;
    hs[idx] = accs;
    float ps = accf * attn[o];
    float pd = accf * attn[DH + o];
    for (int off = 32; off; off >>= 1) {
        ps += __shfl_down(ps, off);
        pd += __shfl_down(pd, off);
    }
    if (o == 0) { s_src[n] = ps; s_dst[n] = pd; }
}

__device__ __forceinline__ unsigned ord_encode(float f) {
    unsigned u = __float_as_uint(f);
    return (u & 0x80000000u) ? ~u : (u | 0x80000000u);
}
__device__ __forceinline__ float ord_decode(unsigned u) {
    return (u & 0x80000000u) ? __uint_as_float(u & 0x7fffffffu) : __uint_as_float(~u);
}

// per edge: logit, leaky_relu, store; segment max via atomicMax on ordered uint
__global__ void k_edge1(const int* __restrict__ src, const int* __restrict__ dst,
                        const float* __restrict__ e_w,
                        const float* __restrict__ s_src, const float* __restrict__ s_dst,
                        const float* __restrict__ consts, int layer,
                        float* __restrict__ e_edge, unsigned* __restrict__ mbuf) {
    int i = blockIdx.x * blockDim.x + threadIdx.x;
    if (i >= N_EDGES) return;
    int s = src[i], d = dst[i];
    float c1 = consts[layer * 2 + 0];
    float c0 = consts[layer * 2 + 1];
    float e = s_src[s] + s_dst[d] + e_w[i] * c1 + c0;
    e = e > 0.f ? e : NEG_SLOPE * e;
    e_edge[i] = e;
    atomicMax(mbuf + d, ord_encode(e));
}

// per edge, 64 lanes: ex = exp(e - m[d]); aggU[d][lane] += ex * z[s][lane]; denom[d] += ex
__global__ void k_edge2(const int* __restrict__ src, const int* __restrict__ dst,
                        const float* __restrict__ e_edge, const unsigned* __restrict__ mbuf,
                        const float* __restrict__ z,
                        float* __restrict__ aggU, float* __restrict__ denom) {
    int t = blockIdx.x * blockDim.x + threadIdx.x;
    int i = t >> 6;
    int lane = t & 63;
    if (i >= N_EDGES) return;
    int s = src[i], d = dst[i];
    float m = ord_decode(mbuf[d]);
    float ex = __expf(e_edge[i] - m);
    atomicAdd(aggU + d * DH + lane, ex * z[s * DH + lane]);
    if (lane == 0) atomicAdd(denom + d, ex);
}

// h = h + relu(denom>0 ? hs + aggU/denom : h)
__global__ void k_node2(float* __restrict__ h, const float* __restrict__ hs,
                        const float* __restrict__ aggU, const float* __restrict__ denom) {
    int idx = blockIdx.x * blockDim.x + threadIdx.x;
    if (idx >= N_NODES * DH) return;
    int n = idx >> 6;
    float hv = h[idx];
    float dn = denom[n];
    float mid = (dn > 0.f) ? (hs[idx] + aggU[idx] / dn) : hv;
    h[idx] = hv + (mid > 0.f ? mid : 0.f);
}

// y = h @ lin1_W^T + b
__global__ void k_final(const float* __restrict__ h, const float* __restrict__ W,
                        const float* __restrict__ b, float* __restrict__ y) {
    int idx = blockIdx.x * blockDim.x + threadIdx.x;
    if (idx >= N_NODES * DOUT) return;
    int n = idx / DOUT, o = idx % DOUT;
    const float4* hrow = (const float4*)(h + n * DH);
    const float4* wrow = (const float4*)(W + o * DH);
    float acc = b[o];
#pragma unroll
    for (int k = 0; k < DH / 4; ++k) {
        float4 hv = hrow[k], wv = wrow[k];
        acc += hv.x * wv.x + hv.y * wv.y + hv.z * wv.z + hv.w * wv.w;
    }
    y[idx] = acc;
}

extern "C" void kernel_launch(void* const* d_in, const int* in_sizes, int n_in,
                              void* d_out, int out_size, void* d_ws, size_t ws_size,
                              hipStream_t stream) {
    const float* feats   = (const float*)d_in[0];
    const float* e_w     = (const float*)d_in[1];
    const int*   src     = (const int*)d_in[4];
    const int*   dst     = (const int*)d_in[5];
    const float* emb_h_W = (const float*)d_in[6];
    const float* emb_h_b = (const float*)d_in[7];
    const float* emb_e_W = (const float*)d_in[8];
    const float* emb_e_b = (const float*)d_in[9];
    const float* Wself[2] = {(const float*)d_in[10], (const float*)d_in[13]};
    const float* Wfunc[2] = {(const float*)d_in[11], (const float*)d_in[14]};
    const float* attn[2]  = {(const float*)d_in[12], (const float*)d_in[15]};
    const float* lin1_W  = (const float*)d_in[16];
    const float* lin1_b  = (const float*)d_in[17];
    float* y = (float*)d_out;

    char* ws = (char*)d_ws;
    size_t off = 0;
    auto alloc = [&](size_t bytes) {
        void* p = ws + off;
        off += (bytes + 255) & ~(size_t)255;
        return p;
    };
    float*    h      = (float*)alloc((size_t)N_NODES * DH * 4);
    float*    z      = (float*)alloc((size_t)N_NODES * DH * 4);
    float*    hs     = (float*)alloc((size_t)N_NODES * DH * 4);
    float*    aggU   = (float*)alloc((size_t)N_NODES * DH * 4);
    float*    e_edge = (float*)alloc((size_t)N_EDGES * 4);
    float*    s_src  = (float*)alloc((size_t)N_NODES * 4);
    float*    s_dst  = (float*)alloc((size_t)N_NODES * 4);
    unsigned* mbuf   = (unsigned*)alloc((size_t)N_NODES * 4);
    float*    denom  = (float*)alloc((size_t)N_NODES * 4);
    float*    consts = (float*)alloc(4 * 4);

    k_consts<<<1, 64, 0, stream>>>(emb_e_W, emb_e_b, attn[0], attn[1], consts);

    const int nNode = N_NODES * DH;
    k_embed<<<(nNode + 255) / 256, 256, 0, stream>>>(feats, emb_h_W, emb_h_b, h);

    for (int l = 0; l < 2; ++l) {
        hipMemsetAsync(aggU, 0, (size_t)N_NODES * DH * 4, stream);
        hipMemsetAsync(mbuf, 0, (size_t)N_NODES * 4, stream);
        hipMemsetAsync(denom, 0, (size_t)N_NODES * 4, stream);
        k_node<<<(nNode + 255) / 256, 256, 0, stream>>>(h, Wself[l], Wfunc[l], attn[l],
                                                        z, hs, s_src, s_dst);
        k_edge1<<<(N_EDGES + 255) / 256, 256, 0, stream>>>(src, dst, e_w, s_src, s_dst,
                                                           consts, l, e_edge, mbuf);
        k_edge2<<<((size_t)N_EDGES * 64 + 255) / 256, 256, 0, stream>>>(src, dst, e_edge, mbuf,
                                                                        z, aggU, denom);
        k_node2<<<(nNode + 255) / 256, 256, 0, stream>>>(h, hs, aggU, denom);
    }

    k_final<<<(N_NODES * DOUT + 255) / 256, 256, 0, stream>>>(h, lin1_W, lin1_b, y);
}

// Round 2
// 888.203 us; speedup vs baseline: 2.2853x; 2.2853x over previous
//
#include <hip/hip_runtime.h>

#define N_NODES 100000
#define N_EDGES 1600000
#define DIN 24
#define DH 64
#define DOUT 12
#define NEG_SLOPE 0.01f
#define SCAN_BLK 2048  // elements per scan block (256 threads x 8)

__device__ __forceinline__ float bcast_f(float v, int srclane) {
    return __uint_as_float(__builtin_amdgcn_readlane(__float_as_uint(v), srclane));
}

// consts[0..3] = {c1_l1, c0_l1, c1_l2, c0_l2} : edge_term = e_w*c1 + c0
__global__ void k_consts(const float* __restrict__ emb_e_W, const float* __restrict__ emb_e_b,
                         const float* __restrict__ attn1, const float* __restrict__ attn2,
                         float* __restrict__ consts) {
    int lane = threadIdx.x; // 64 threads = 1 wave
    float w = emb_e_W[lane];
    float b = emb_e_b[lane];
    float a1 = attn1[2 * DH + lane];
    float a2 = attn2[2 * DH + lane];
    float c11 = w * a1, c01 = b * a1, c12 = w * a2, c02 = b * a2;
    for (int off = 32; off; off >>= 1) {
        c11 += __shfl_down(c11, off);
        c01 += __shfl_down(c01, off);
        c12 += __shfl_down(c12, off);
        c02 += __shfl_down(c02, off);
    }
    if (lane == 0) {
        consts[0] = c11; consts[1] = c01; consts[2] = c12; consts[3] = c02;
    }
}

__global__ void k_embed(const float* __restrict__ feats, const float* __restrict__ W,
                        const float* __restrict__ b, float* __restrict__ h) {
    int idx = blockIdx.x * blockDim.x + threadIdx.x;
    if (idx >= N_NODES * DH) return;
    int n = idx >> 6, o = idx & 63;
    const float* f = feats + n * DIN;
    const float* w = W + o * DIN;
    float acc = b[o];
#pragma unroll
    for (int k = 0; k < DIN; ++k) acc += f[k] * w[k];
    h[idx] = acc;
}

// ---------------- CSR build ----------------
__global__ void k_hist(const int* __restrict__ dst, int* __restrict__ deg) {
    int i = blockIdx.x * blockDim.x + threadIdx.x;
    if (i >= N_EDGES) return;
    atomicAdd(deg + dst[i], 1);
}

// blockwise exclusive scan: writes per-element exclusive (local) into row_off, block sums into part
__global__ void k_scan1(const int* __restrict__ deg, int* __restrict__ row_off,
                        int* __restrict__ part) {
    __shared__ int lds[256];
    int t = threadIdx.x;
    int base = blockIdx.x * SCAN_BLK + t * 8;
    int v[8];
    int s = 0;
#pragma unroll
    for (int i = 0; i < 8; ++i) {
        int idx = base + i;
        v[i] = (idx < N_NODES) ? deg[idx] : 0;
        s += v[i];
    }
    lds[t] = s;
    __syncthreads();
    for (int off = 1; off < 256; off <<= 1) {
        int y = (t >= off) ? lds[t - off] : 0;
        __syncthreads();
        lds[t] += y;
        __syncthreads();
    }
    int run = lds[t] - s; // exclusive base for this thread within block
#pragma unroll
    for (int i = 0; i < 8; ++i) {
        int idx = base + i;
        if (idx < N_NODES) row_off[idx] = run;
        run += v[i];
    }
    if (t == 255) part[blockIdx.x] = lds[255];
}

// single-wave exclusive scan of the block partials (nblk <= 64)
__global__ void k_scan2(int* __restrict__ part, int nblk) {
    int lane = threadIdx.x;
    int orig = (lane < nblk) ? part[lane] : 0;
    int v = orig;
    for (int off = 1; off < 64; off <<= 1) {
        int y = __shfl_up(v, off);
        if (lane >= off) v += y;
    }
    if (lane < nblk) part[lane] = v - orig; // exclusive
}

__global__ void k_scan3(int* __restrict__ row_off, const int* __restrict__ part,
                        int* __restrict__ cursor) {
    int i = blockIdx.x * blockDim.x + threadIdx.x;
    if (i >= N_NODES) return;
    int v = row_off[i] + part[i / SCAN_BLK];
    row_off[i] = v;
    cursor[i] = v;
    if (i == 0) row_off[N_NODES] = N_EDGES;
}

__global__ void k_scatter(const int* __restrict__ src, const int* __restrict__ dst,
                          const float* __restrict__ e_w,
                          int* __restrict__ cursor,
                          int* __restrict__ csr_src, float* __restrict__ csr_ew) {
    int i = blockIdx.x * blockDim.x + threadIdx.x;
    if (i >= N_EDGES) return;
    int d = dst[i];
    int pos = atomicAdd(cursor + d, 1);
    csr_src[pos] = src[i];
    csr_ew[pos] = e_w[i];
}

// ---------------- per-layer node GEMM ----------------
// 4 nodes per wave; lane = output channel; h broadcast via v_readlane (const idx)
__global__ void k_node(const float* __restrict__ h,
                       const float* __restrict__ Wself, const float* __restrict__ Wfunc,
                       const float* __restrict__ attn,
                       float* __restrict__ z, float* __restrict__ hs,
                       float* __restrict__ s_src, float* __restrict__ s_dst) {
    int wave = threadIdx.x >> 6, lane = threadIdx.x & 63;
    int n0 = (blockIdx.x * 4 + wave) * 4;
    if (n0 >= N_NODES) return;
    float hreg[4];
#pragma unroll
    for (int m = 0; m < 4; ++m) {
        int n = n0 + m;
        hreg[m] = (n < N_NODES) ? h[n * DH + lane] : 0.f;
    }
    const float4* ws = (const float4*)(Wself + lane * DH);
    const float4* wf = (const float4*)(Wfunc + lane * DH);
    float accs[4] = {0.f, 0.f, 0.f, 0.f};
    float accf[4] = {0.f, 0.f, 0.f, 0.f};
#pragma unroll
    for (int kc = 0; kc < 16; ++kc) {
        float4 a = ws[kc];
        float4 b = wf[kc];
#pragma unroll
        for (int m = 0; m < 4; ++m) {
            float h0 = bcast_f(hreg[m], 4 * kc + 0);
            float h1 = bcast_f(hreg[m], 4 * kc + 1);
            float h2 = bcast_f(hreg[m], 4 * kc + 2);
            float h3 = bcast_f(hreg[m], 4 * kc + 3);
            accs[m] += h0 * a.x + h1 * a.y + h2 * a.z + h3 * a.w;
            accf[m] += h0 * b.x + h1 * b.y + h2 * b.z + h3 * b.w;
        }
    }
    float a_s = attn[lane], a_d = attn[DH + lane];
#pragma unroll
    for (int m = 0; m < 4; ++m) {
        int n = n0 + m;
        if (n < N_NODES) {
            z[n * DH + lane] = accf[m];
            hs[n * DH + lane] = accs[m];
            float ps = accf[m] * a_s;
            float pd = accf[m] * a_d;
            for (int off = 32; off; off >>= 1) {
                ps += __shfl_down(ps, off);
                pd += __shfl_down(pd, off);
            }
            if (lane == 0) { s_src[n] = ps; s_dst[n] = pd; }
        }
    }
}

// ---------------- fused edge softmax + aggregation (gather, no atomics) ----------------
// one wave per destination node
__global__ void k_agg(const int* __restrict__ row_off, const int* __restrict__ csr_src,
                      const float* __restrict__ csr_ew,
                      const float* __restrict__ s_src, const float* __restrict__ s_dstA,
                      const float* __restrict__ consts, int layer,
                      const float* __restrict__ z, const float* __restrict__ hsb,
                      float* __restrict__ h) {
    int wave = threadIdx.x >> 6, lane = threadIdx.x & 63;
    int n = blockIdx.x * 4 + wave;
    if (n >= N_NODES) return;
    int rs = row_off[n], re = row_off[n + 1];
    int deg = re - rs;
    float hold = h[n * DH + lane];
    if (deg == 0) {
        h[n * DH + lane] = hold + fmaxf(hold, 0.f);
        return;
    }
    float c1 = consts[layer * 2 + 0];
    float c0 = consts[layer * 2 + 1];
    float sd = s_dstA[n];

    // phase 1: per-edge logits (chunk 0 cached in regs), wave max
    float e0 = -1e30f;
    int s0 = 0;
    if (lane < deg) {
        int j = rs + lane;
        s0 = csr_src[j];
        float e = s_src[s0] + sd + csr_ew[j] * c1 + c0;
        e0 = (e > 0.f) ? e : NEG_SLOPE * e;
    }
    float m = e0;
    for (int base = 64; base < deg; base += 64) {
        if (base + lane < deg) {
            int j = rs + base + lane;
            int si = csr_src[j];
            float e = s_src[si] + sd + csr_ew[j] * c1 + c0;
            e = (e > 0.f) ? e : NEG_SLOPE * e;
            m = fmaxf(m, e);
        }
    }
    for (int off = 32; off; off >>= 1) m = fmaxf(m, __shfl_xor(m, off));

    // phase 2+3: exp, denom partials, accumulate ex * z[src] (lane = channel)
    float acc = 0.f, ssum = 0.f;
    {
        int cnt = (deg < 64) ? deg : 64;
        float ex = (lane < cnt) ? __expf(e0 - m) : 0.f;
        ssum = ex;
        int b = 0;
        for (; b + 1 < cnt; b += 2) {
            float exb0 = bcast_f(ex, b);
            int sb0 = __builtin_amdgcn_readlane(s0, b);
            float exb1 = bcast_f(ex, b + 1);
            int sb1 = __builtin_amdgcn_readlane(s0, b + 1);
            float z0 = z[(sb0 << 6) + lane];
            float z1 = z[(sb1 << 6) + lane];
            acc += exb0 * z0;
            acc += exb1 * z1;
        }
        if (b < cnt) {
            float exb = bcast_f(ex, b);
            int sb = __builtin_amdgcn_readlane(s0, b);
            acc += exb * z[(sb << 6) + lane];
        }
    }
    for (int base = 64; base < deg; base += 64) { // rare tail (deg > 64)
        float ex = 0.f;
        int si = 0;
        if (base + lane < deg) {
            int j = rs + base + lane;
            si = csr_src[j];
            float e = s_src[si] + sd + csr_ew[j] * c1 + c0;
            e = (e > 0.f) ? e : NEG_SLOPE * e;
            ex = __expf(e - m);
        }
        ssum += ex;
        int cnt = deg - base;
        if (cnt > 64) cnt = 64;
        for (int b = 0; b < cnt; ++b) {
            float exb = bcast_f(ex, b);
            int sb = __builtin_amdgcn_readlane(si, b);
            acc += exb * z[(sb << 6) + lane];
        }
    }
    for (int off = 32; off; off >>= 1) ssum += __shfl_xor(ssum, off);

    float hmid = hsb[n * DH + lane] + acc / ssum;
    h[n * DH + lane] = hold + fmaxf(hmid, 0.f);
}

__global__ void k_final(const float* __restrict__ h, const float* __restrict__ W,
                        const float* __restrict__ b, float* __restrict__ y) {
    int idx = blockIdx.x * blockDim.x + threadIdx.x;
    if (idx >= N_NODES * DOUT) return;
    int n = idx / DOUT, o = idx % DOUT;
    const float4* hrow = (const float4*)(h + n * DH);
    const float4* wrow = (const float4*)(W + o * DH);
    float acc = b[o];
#pragma unroll
    for (int k = 0; k < DH / 4; ++k) {
        float4 hv = hrow[k], wv = wrow[k];
        acc += hv.x * wv.x + hv.y * wv.y + hv.z * wv.z + hv.w * wv.w;
    }
    y[idx] = acc;
}

extern "C" void kernel_launch(void* const* d_in, const int* in_sizes, int n_in,
                              void* d_out, int out_size, void* d_ws, size_t ws_size,
                              hipStream_t stream) {
    const float* feats   = (const float*)d_in[0];
    const float* e_w     = (const float*)d_in[1];
    const int*   src     = (const int*)d_in[4];
    const int*   dst     = (const int*)d_in[5];
    const float* emb_h_W = (const float*)d_in[6];
    const float* emb_h_b = (const float*)d_in[7];
    const float* emb_e_W = (const float*)d_in[8];
    const float* emb_e_b = (const float*)d_in[9];
    const float* Wself[2] = {(const float*)d_in[10], (const float*)d_in[13]};
    const float* Wfunc[2] = {(const float*)d_in[11], (const float*)d_in[14]};
    const float* attn[2]  = {(const float*)d_in[12], (const float*)d_in[15]};
    const float* lin1_W  = (const float*)d_in[16];
    const float* lin1_b  = (const float*)d_in[17];
    float* y = (float*)d_out;

    char* ws = (char*)d_ws;
    size_t off = 0;
    auto alloc = [&](size_t bytes) {
        void* p = ws + off;
        off += (bytes + 255) & ~(size_t)255;
        return p;
    };
    float* h       = (float*)alloc((size_t)N_NODES * DH * 4);
    float* z       = (float*)alloc((size_t)N_NODES * DH * 4);
    float* hs      = (float*)alloc((size_t)N_NODES * DH * 4);
    int*   csr_src = (int*)alloc((size_t)N_EDGES * 4);
    float* csr_ew  = (float*)alloc((size_t)N_EDGES * 4);
    float* s_src   = (float*)alloc((size_t)N_NODES * 4);
    float* s_dst   = (float*)alloc((size_t)N_NODES * 4);
    int*   row_off = (int*)alloc((size_t)(N_NODES + 1) * 4);
    int*   cursor  = (int*)alloc((size_t)N_NODES * 4);
    int*   deg     = (int*)alloc((size_t)N_NODES * 4);
    int*   part    = (int*)alloc(256 * 4);
    float* consts  = (float*)alloc(4 * 4);

    const int nblk_scan = (N_NODES + SCAN_BLK - 1) / SCAN_BLK; // 49

    k_consts<<<1, 64, 0, stream>>>(emb_e_W, emb_e_b, attn[0], attn[1], consts);

    const int nNode = N_NODES * DH;
    k_embed<<<(nNode + 255) / 256, 256, 0, stream>>>(feats, emb_h_W, emb_h_b, h);

    // CSR build (graph identical for both layers)
    hipMemsetAsync(deg, 0, (size_t)N_NODES * 4, stream);
    k_hist<<<(N_EDGES + 255) / 256, 256, 0, stream>>>(dst, deg);
    k_scan1<<<nblk_scan, 256, 0, stream>>>(deg, row_off, part);
    k_scan2<<<1, 64, 0, stream>>>(part, nblk_scan);
    k_scan3<<<(N_NODES + 255) / 256, 256, 0, stream>>>(row_off, part, cursor);
    k_scatter<<<(N_EDGES + 255) / 256, 256, 0, stream>>>(src, dst, e_w, cursor, csr_src, csr_ew);

    for (int l = 0; l < 2; ++l) {
        // 4 nodes per wave, 4 waves per block -> 16 nodes per block
        k_node<<<(N_NODES + 15) / 16, 256, 0, stream>>>(h, Wself[l], Wfunc[l], attn[l],
                                                        z, hs, s_src, s_dst);
        // 1 node per wave, 4 waves per block
        k_agg<<<(N_NODES + 3) / 4, 256, 0, stream>>>(row_off, csr_src, csr_ew,
                                                     s_src, s_dst, consts, l, z, hs, h);
    }

    k_final<<<(N_NODES * DOUT + 255) / 256, 256, 0, stream>>>(h, lin1_W, lin1_b, y);
}

// Round 3
// 695.990 us; speedup vs baseline: 2.9164x; 1.2762x over previous
//
#include <hip/hip_runtime.h>
#include <hip/hip_fp16.h>

#define N_NODES 100000
#define N_EDGES 1600000
#define DIN 24
#define DH 64
#define DOUT 12
#define NEG_SLOPE 0.01f
#define SCAN_BLK 2048  // elements per scan block (256 threads x 8)

__device__ __forceinline__ float bcast_f(float v, int srclane) {
    return __uint_as_float(__builtin_amdgcn_readlane(__float_as_uint(v), srclane));
}

// consts[0..3] = {c1_l1, c0_l1, c1_l2, c0_l2} : edge_term = e_w*c1 + c0
__global__ void k_consts(const float* __restrict__ emb_e_W, const float* __restrict__ emb_e_b,
                         const float* __restrict__ attn1, const float* __restrict__ attn2,
                         float* __restrict__ consts) {
    int lane = threadIdx.x; // 64 threads = 1 wave
    float w = emb_e_W[lane];
    float b = emb_e_b[lane];
    float a1 = attn1[2 * DH + lane];
    float a2 = attn2[2 * DH + lane];
    float c11 = w * a1, c01 = b * a1, c12 = w * a2, c02 = b * a2;
    for (int off = 32; off; off >>= 1) {
        c11 += __shfl_down(c11, off);
        c01 += __shfl_down(c01, off);
        c12 += __shfl_down(c12, off);
        c02 += __shfl_down(c02, off);
    }
    if (lane == 0) {
        consts[0] = c11; consts[1] = c01; consts[2] = c12; consts[3] = c02;
    }
}

__global__ void k_embed(const float* __restrict__ feats, const float* __restrict__ W,
                        const float* __restrict__ b, float* __restrict__ h) {
    int idx = blockIdx.x * blockDim.x + threadIdx.x;
    if (idx >= N_NODES * DH) return;
    int n = idx >> 6, o = idx & 63;
    const float* f = feats + n * DIN;
    const float* w = W + o * DIN;
    float acc = b[o];
#pragma unroll
    for (int k = 0; k < DIN; ++k) acc += f[k] * w[k];
    h[idx] = acc;
}

// ---------------- CSR build ----------------
__global__ void k_hist(const int* __restrict__ dst, int* __restrict__ deg) {
    int i = blockIdx.x * blockDim.x + threadIdx.x;
    if (i >= N_EDGES) return;
    atomicAdd(deg + dst[i], 1);
}

__global__ void k_scan1(const int* __restrict__ deg, int* __restrict__ row_off,
                        int* __restrict__ part) {
    __shared__ int lds[256];
    int t = threadIdx.x;
    int base = blockIdx.x * SCAN_BLK + t * 8;
    int v[8];
    int s = 0;
#pragma unroll
    for (int i = 0; i < 8; ++i) {
        int idx = base + i;
        v[i] = (idx < N_NODES) ? deg[idx] : 0;
        s += v[i];
    }
    lds[t] = s;
    __syncthreads();
    for (int off = 1; off < 256; off <<= 1) {
        int y = (t >= off) ? lds[t - off] : 0;
        __syncthreads();
        lds[t] += y;
        __syncthreads();
    }
    int run = lds[t] - s;
#pragma unroll
    for (int i = 0; i < 8; ++i) {
        int idx = base + i;
        if (idx < N_NODES) row_off[idx] = run;
        run += v[i];
    }
    if (t == 255) part[blockIdx.x] = lds[255];
}

__global__ void k_scan2(int* __restrict__ part, int nblk) {
    int lane = threadIdx.x;
    int orig = (lane < nblk) ? part[lane] : 0;
    int v = orig;
    for (int off = 1; off < 64; off <<= 1) {
        int y = __shfl_up(v, off);
        if (lane >= off) v += y;
    }
    if (lane < nblk) part[lane] = v - orig;
}

__global__ void k_scan3(int* __restrict__ row_off, const int* __restrict__ part,
                        int* __restrict__ cursor) {
    int i = blockIdx.x * blockDim.x + threadIdx.x;
    if (i >= N_NODES) return;
    int v = row_off[i] + part[i / SCAN_BLK];
    row_off[i] = v;
    cursor[i] = v;
    if (i == 0) row_off[N_NODES] = N_EDGES;
}

__global__ void k_scatter(const int* __restrict__ src, const int* __restrict__ dst,
                          const float* __restrict__ e_w,
                          int* __restrict__ cursor,
                          int* __restrict__ csr_src, float* __restrict__ csr_ew) {
    int i = blockIdx.x * blockDim.x + threadIdx.x;
    if (i >= N_EDGES) return;
    int d = dst[i];
    int pos = atomicAdd(cursor + d, 1);
    csr_src[pos] = src[i];
    csr_ew[pos] = e_w[i];
}

// ---------------- per-layer node GEMM ----------------
// 8 nodes per wave; lane = output channel; h broadcast via v_readlane (const idx)
// __launch_bounds__(256,2): cap 128 VGPRs -> no scratch spill (round-2 k_node
// at default cap 64 VGPRs spilled: 280 MB scratch WRITE_SIZE, 191 us)
__global__ void __launch_bounds__(256, 2)
k_node(const float* __restrict__ h,
       const float* __restrict__ Wself, const float* __restrict__ Wfunc,
       const float* __restrict__ attn,
       __half* __restrict__ zh, float* __restrict__ hs,
       float* __restrict__ s_src, float* __restrict__ s_dst) {
    int wave = threadIdx.x >> 6, lane = threadIdx.x & 63;
    int n0 = (blockIdx.x * 4 + wave) * 8;
    if (n0 >= N_NODES) return;
    float hreg[8];
#pragma unroll
    for (int m = 0; m < 8; ++m) {
        int n = n0 + m;
        hreg[m] = (n < N_NODES) ? h[n * DH + lane] : 0.f;
    }
    const float4* ws = (const float4*)(Wself + lane * DH);
    const float4* wf = (const float4*)(Wfunc + lane * DH);
    float accs[8] = {0.f, 0.f, 0.f, 0.f, 0.f, 0.f, 0.f, 0.f};
    float accf[8] = {0.f, 0.f, 0.f, 0.f, 0.f, 0.f, 0.f, 0.f};
#pragma unroll
    for (int kc = 0; kc < 16; ++kc) {
        float4 a = ws[kc];
        float4 b = wf[kc];
#pragma unroll
        for (int m = 0; m < 8; ++m) {
            float h0 = bcast_f(hreg[m], 4 * kc + 0);
            float h1 = bcast_f(hreg[m], 4 * kc + 1);
            float h2 = bcast_f(hreg[m], 4 * kc + 2);
            float h3 = bcast_f(hreg[m], 4 * kc + 3);
            accs[m] += h0 * a.x + h1 * a.y + h2 * a.z + h3 * a.w;
            accf[m] += h0 * b.x + h1 * b.y + h2 * b.z + h3 * b.w;
        }
    }
    float a_s = attn[lane], a_d = attn[DH + lane];
#pragma unroll
    for (int m = 0; m < 8; ++m) {
        int n = n0 + m;
        if (n < N_NODES) {
            zh[n * DH + lane] = __float2half(accf[m]);
            hs[n * DH + lane] = accs[m];
            float ps = accf[m] * a_s;
            float pd = accf[m] * a_d;
            for (int off = 32; off; off >>= 1) {
                ps += __shfl_down(ps, off);
                pd += __shfl_down(pd, off);
            }
            if (lane == 0) { s_src[n] = ps; s_dst[n] = pd; }
        }
    }
}

// ---------------- fused edge softmax + aggregation (gather, no atomics) ----------------
// one wave per destination node; z gathered as fp16 (128 B / edge)
__global__ void k_agg(const int* __restrict__ row_off, const int* __restrict__ csr_src,
                      const float* __restrict__ csr_ew,
                      const float* __restrict__ s_src, const float* __restrict__ s_dstA,
                      const float* __restrict__ consts, int layer,
                      const __half* __restrict__ zh, const float* __restrict__ hsb,
                      float* __restrict__ h) {
    int wave = threadIdx.x >> 6, lane = threadIdx.x & 63;
    int n = blockIdx.x * 4 + wave;
    if (n >= N_NODES) return;
    int rs = row_off[n], re = row_off[n + 1];
    int deg = re - rs;
    float hold = h[n * DH + lane];
    if (deg == 0) {
        h[n * DH + lane] = hold + fmaxf(hold, 0.f);
        return;
    }
    float c1 = consts[layer * 2 + 0];
    float c0 = consts[layer * 2 + 1];
    float sd = s_dstA[n];

    // phase 1: per-edge logits (chunk 0 cached in regs), wave max
    float e0 = -1e30f;
    int s0 = 0;
    if (lane < deg) {
        int j = rs + lane;
        s0 = csr_src[j];
        float e = s_src[s0] + sd + csr_ew[j] * c1 + c0;
        e0 = (e > 0.f) ? e : NEG_SLOPE * e;
    }
    float m = e0;
    for (int base = 64; base < deg; base += 64) {
        if (base + lane < deg) {
            int j = rs + base + lane;
            int si = csr_src[j];
            float e = s_src[si] + sd + csr_ew[j] * c1 + c0;
            e = (e > 0.f) ? e : NEG_SLOPE * e;
            m = fmaxf(m, e);
        }
    }
    for (int off = 32; off; off >>= 1) m = fmaxf(m, __shfl_xor(m, off));

    // phase 2+3: exp, denom partials, accumulate ex * z[src] (lane = channel)
    float acc = 0.f, ssum = 0.f;
    {
        int cnt = (deg < 64) ? deg : 64;
        float ex = (lane < cnt) ? __expf(e0 - m) : 0.f;
        ssum = ex;
        int b = 0;
        for (; b + 3 < cnt; b += 4) {
            float exb0 = bcast_f(ex, b);
            int sb0 = __builtin_amdgcn_readlane(s0, b);
            float exb1 = bcast_f(ex, b + 1);
            int sb1 = __builtin_amdgcn_readlane(s0, b + 1);
            float exb2 = bcast_f(ex, b + 2);
            int sb2 = __builtin_amdgcn_readlane(s0, b + 2);
            float exb3 = bcast_f(ex, b + 3);
            int sb3 = __builtin_amdgcn_readlane(s0, b + 3);
            float z0 = __half2float(zh[(sb0 << 6) + lane]);
            float z1 = __half2float(zh[(sb1 << 6) + lane]);
            float z2 = __half2float(zh[(sb2 << 6) + lane]);
            float z3 = __half2float(zh[(sb3 << 6) + lane]);
            acc += exb0 * z0;
            acc += exb1 * z1;
            acc += exb2 * z2;
            acc += exb3 * z3;
        }
        for (; b < cnt; ++b) {
            float exb = bcast_f(ex, b);
            int sb = __builtin_amdgcn_readlane(s0, b);
            acc += exb * __half2float(zh[(sb << 6) + lane]);
        }
    }
    for (int base = 64; base < deg; base += 64) { // rare tail (deg > 64)
        float ex = 0.f;
        int si = 0;
        if (base + lane < deg) {
            int j = rs + base + lane;
            si = csr_src[j];
            float e = s_src[si] + sd + csr_ew[j] * c1 + c0;
            e = (e > 0.f) ? e : NEG_SLOPE * e;
            ex = __expf(e - m);
        }
        ssum += ex;
        int cnt = deg - base;
        if (cnt > 64) cnt = 64;
        for (int b = 0; b < cnt; ++b) {
            float exb = bcast_f(ex, b);
            int sb = __builtin_amdgcn_readlane(si, b);
            acc += exb * __half2float(zh[(sb << 6) + lane]);
        }
    }
    for (int off = 32; off; off >>= 1) ssum += __shfl_xor(ssum, off);

    float hmid = hsb[n * DH + lane] + acc / ssum;
    h[n * DH + lane] = hold + fmaxf(hmid, 0.f);
}

__global__ void k_final(const float* __restrict__ h, const float* __restrict__ W,
                        const float* __restrict__ b, float* __restrict__ y) {
    int idx = blockIdx.x * blockDim.x + threadIdx.x;
    if (idx >= N_NODES * DOUT) return;
    int n = idx / DOUT, o = idx % DOUT;
    const float4* hrow = (const float4*)(h + n * DH);
    const float4* wrow = (const float4*)(W + o * DH);
    float acc = b[o];
#pragma unroll
    for (int k = 0; k < DH / 4; ++k) {
        float4 hv = hrow[k], wv = wrow[k];
        acc += hv.x * wv.x + hv.y * wv.y + hv.z * wv.z + hv.w * wv.w;
    }
    y[idx] = acc;
}

extern "C" void kernel_launch(void* const* d_in, const int* in_sizes, int n_in,
                              void* d_out, int out_size, void* d_ws, size_t ws_size,
                              hipStream_t stream) {
    const float* feats   = (const float*)d_in[0];
    const float* e_w     = (const float*)d_in[1];
    const int*   src     = (const int*)d_in[4];
    const int*   dst     = (const int*)d_in[5];
    const float* emb_h_W = (const float*)d_in[6];
    const float* emb_h_b = (const float*)d_in[7];
    const float* emb_e_W = (const float*)d_in[8];
    const float* emb_e_b = (const float*)d_in[9];
    const float* Wself[2] = {(const float*)d_in[10], (const float*)d_in[13]};
    const float* Wfunc[2] = {(const float*)d_in[11], (const float*)d_in[14]};
    const float* attn[2]  = {(const float*)d_in[12], (const float*)d_in[15]};
    const float* lin1_W  = (const float*)d_in[16];
    const float* lin1_b  = (const float*)d_in[17];
    float* y = (float*)d_out;

    char* ws = (char*)d_ws;
    size_t off = 0;
    auto alloc = [&](size_t bytes) {
        void* p = ws + off;
        off += (bytes + 255) & ~(size_t)255;
        return p;
    };
    float*  h       = (float*)alloc((size_t)N_NODES * DH * 4);
    __half* zh      = (__half*)alloc((size_t)N_NODES * DH * 2);
    float*  hs      = (float*)alloc((size_t)N_NODES * DH * 4);
    int*    csr_src = (int*)alloc((size_t)N_EDGES * 4);
    float*  csr_ew  = (float*)alloc((size_t)N_EDGES * 4);
    float*  s_src   = (float*)alloc((size_t)N_NODES * 4);
    float*  s_dst   = (float*)alloc((size_t)N_NODES * 4);
    int*    row_off = (int*)alloc((size_t)(N_NODES + 1) * 4);
    int*    cursor  = (int*)alloc((size_t)N_NODES * 4);
    int*    deg     = (int*)alloc((size_t)N_NODES * 4);
    int*    part    = (int*)alloc(256 * 4);
    float*  consts  = (float*)alloc(4 * 4);

    const int nblk_scan = (N_NODES + SCAN_BLK - 1) / SCAN_BLK; // 49

    k_consts<<<1, 64, 0, stream>>>(emb_e_W, emb_e_b, attn[0], attn[1], consts);

    const int nNode = N_NODES * DH;
    k_embed<<<(nNode + 255) / 256, 256, 0, stream>>>(feats, emb_h_W, emb_h_b, h);

    // CSR build (graph identical for both layers)
    hipMemsetAsync(deg, 0, (size_t)N_NODES * 4, stream);
    k_hist<<<(N_EDGES + 255) / 256, 256, 0, stream>>>(dst, deg);
    k_scan1<<<nblk_scan, 256, 0, stream>>>(deg, row_off, part);
    k_scan2<<<1, 64, 0, stream>>>(part, nblk_scan);
    k_scan3<<<(N_NODES + 255) / 256, 256, 0, stream>>>(row_off, part, cursor);
    k_scatter<<<(N_EDGES + 255) / 256, 256, 0, stream>>>(src, dst, e_w, cursor, csr_src, csr_ew);

    for (int l = 0; l < 2; ++l) {
        // 8 nodes per wave, 4 waves per block -> 32 nodes per block
        k_node<<<(N_NODES + 31) / 32, 256, 0, stream>>>(h, Wself[l], Wfunc[l], attn[l],
                                                        zh, hs, s_src, s_dst);
        // 1 node per wave, 4 waves per block
        k_agg<<<(N_NODES + 3) / 4, 256, 0, stream>>>(row_off, csr_src, csr_ew,
                                                     s_src, s_dst, consts, l, zh, hs, h);
    }

    k_final<<<(N_NODES * DOUT + 255) / 256, 256, 0, stream>>>(h, lin1_W, lin1_b, y);
}

// Round 4
// 632.771 us; speedup vs baseline: 3.2078x; 1.0999x over previous
//
#include <hip/hip_runtime.h>
#include <hip/hip_fp16.h>

#define N_NODES 100000
#define N_EDGES 1600000
#define DIN 24
#define DH 64
#define DOUT 12
#define NEG_SLOPE 0.01f
#define SCAN_BLK 2048   // elements per scan block (256 threads x 8)
#define SLICE 12500     // N_NODES / 8 : dst-space slice per XCD group
#define NCHUNK 128      // edge chunks for sliced kernels
#define ECH ((N_EDGES + NCHUNK - 1) / NCHUNK)  // 12500 edges per chunk

__device__ __forceinline__ float bcast_f(float v, int srclane) {
    return __uint_as_float(__builtin_amdgcn_readlane(__float_as_uint(v), srclane));
}

// consts[0..3] = {c1_l1, c0_l1, c1_l2, c0_l2} : edge_term = e_w*c1 + c0
__global__ void k_consts(const float* __restrict__ emb_e_W, const float* __restrict__ emb_e_b,
                         const float* __restrict__ attn1, const float* __restrict__ attn2,
                         float* __restrict__ consts) {
    int lane = threadIdx.x;
    float w = emb_e_W[lane];
    float b = emb_e_b[lane];
    float a1 = attn1[2 * DH + lane];
    float a2 = attn2[2 * DH + lane];
    float c11 = w * a1, c01 = b * a1, c12 = w * a2, c02 = b * a2;
    for (int off = 32; off; off >>= 1) {
        c11 += __shfl_down(c11, off);
        c01 += __shfl_down(c01, off);
        c12 += __shfl_down(c12, off);
        c02 += __shfl_down(c02, off);
    }
    if (lane == 0) {
        consts[0] = c11; consts[1] = c01; consts[2] = c12; consts[3] = c02;
    }
}

__global__ void k_embed(const float* __restrict__ feats, const float* __restrict__ W,
                        const float* __restrict__ b, float* __restrict__ h) {
    int idx = blockIdx.x * blockDim.x + threadIdx.x;
    if (idx >= N_NODES * DH) return;
    int n = idx >> 6, o = idx & 63;
    const float* f = feats + n * DIN;
    const float* w = W + o * DIN;
    float acc = b[o];
#pragma unroll
    for (int k = 0; k < DIN; ++k) acc += f[k] * w[k];
    h[idx] = acc;
}

// ---------------- CSR build ----------------
// pack (src 17b | e_w q15 << 17) — one 4B payload per edge
__global__ void k_pack(const int* __restrict__ src, const float* __restrict__ e_w,
                       unsigned* __restrict__ tmp) {
    int i = blockIdx.x * blockDim.x + threadIdx.x;
    if (i >= N_EDGES) return;
    unsigned q = (unsigned)(e_w[i] * 32768.f);
    if (q > 32767u) q = 32767u;
    tmp[i] = (unsigned)src[i] | (q << 17);
}

// XCD-sliced histogram: group g = blockIdx&7 handles dst in [g*SLICE,(g+1)*SLICE)
// -> deg[] cache lines only dirtied from one XCD (no cross-XCD line ping-pong)
__global__ void k_hist(const int* __restrict__ dst, int* __restrict__ deg) {
    int g = blockIdx.x & 7;
    int start = (blockIdx.x >> 3) * ECH;
    int end = start + ECH;
    if (end > N_EDGES) end = N_EDGES;
    for (int i = start + threadIdx.x; i < end; i += 256) {
        int d = dst[i];
        if ((unsigned)d / SLICE == (unsigned)g) atomicAdd(deg + d, 1);
    }
}

__global__ void k_scan1(const int* __restrict__ deg, int* __restrict__ row_off,
                        int* __restrict__ part) {
    __shared__ int lds[256];
    int t = threadIdx.x;
    int base = blockIdx.x * SCAN_BLK + t * 8;
    int v[8];
    int s = 0;
#pragma unroll
    for (int i = 0; i < 8; ++i) {
        int idx = base + i;
        v[i] = (idx < N_NODES) ? deg[idx] : 0;
        s += v[i];
    }
    lds[t] = s;
    __syncthreads();
    for (int off = 1; off < 256; off <<= 1) {
        int y = (t >= off) ? lds[t - off] : 0;
        __syncthreads();
        lds[t] += y;
        __syncthreads();
    }
    int run = lds[t] - s;
#pragma unroll
    for (int i = 0; i < 8; ++i) {
        int idx = base + i;
        if (idx < N_NODES) row_off[idx] = run;
        run += v[i];
    }
    if (t == 255) part[blockIdx.x] = lds[255];
}

__global__ void k_scan2(int* __restrict__ part, int nblk) {
    int lane = threadIdx.x;
    int orig = (lane < nblk) ? part[lane] : 0;
    int v = orig;
    for (int off = 1; off < 64; off <<= 1) {
        int y = __shfl_up(v, off);
        if (lane >= off) v += y;
    }
    if (lane < nblk) part[lane] = v - orig;
}

__global__ void k_scan3(int* __restrict__ row_off, const int* __restrict__ part,
                        int* __restrict__ cursor) {
    int i = blockIdx.x * blockDim.x + threadIdx.x;
    if (i >= N_NODES) return;
    int v = row_off[i] + part[i / SCAN_BLK];
    row_off[i] = v;
    cursor[i] = v;
    if (i == 0) row_off[N_NODES] = N_EDGES;
}

// XCD-sliced scatter: group g only places edges with dst in its slice, so the
// CSR region [row_off[g*SLICE], row_off[(g+1)*SLICE]) and cursor lines are
// written from a single XCD -> L2 write-combining works, writeback once.
__global__ void k_scatter(const int* __restrict__ dst, const unsigned* __restrict__ tmp,
                          int* __restrict__ cursor, unsigned* __restrict__ csr) {
    int g = blockIdx.x & 7;
    int start = (blockIdx.x >> 3) * ECH;
    int end = start + ECH;
    if (end > N_EDGES) end = N_EDGES;
    for (int i = start + threadIdx.x; i < end; i += 256) {
        int d = dst[i];
        if ((unsigned)d / SLICE == (unsigned)g) {
            int pos = atomicAdd(cursor + d, 1);
            csr[pos] = tmp[i];
        }
    }
}

// ---------------- per-layer node GEMM ----------------
// 8 nodes per wave; lane = output channel; h broadcast via v_readlane.
// __launch_bounds__(256,2): cap 128 VGPRs -> no scratch spill.
__global__ void __launch_bounds__(256, 2)
k_node(const float* __restrict__ h,
       const float* __restrict__ Wself, const float* __restrict__ Wfunc,
       const float* __restrict__ attn,
       __half* __restrict__ zh, float* __restrict__ hs,
       float* __restrict__ s_src, float* __restrict__ s_dst) {
    int wave = threadIdx.x >> 6, lane = threadIdx.x & 63;
    int n0 = (blockIdx.x * 4 + wave) * 8;
    if (n0 >= N_NODES) return;
    float hreg[8];
#pragma unroll
    for (int m = 0; m < 8; ++m) {
        int n = n0 + m;
        hreg[m] = (n < N_NODES) ? h[n * DH + lane] : 0.f;
    }
    const float4* ws = (const float4*)(Wself + lane * DH);
    const float4* wf = (const float4*)(Wfunc + lane * DH);
    float accs[8] = {0.f, 0.f, 0.f, 0.f, 0.f, 0.f, 0.f, 0.f};
    float accf[8] = {0.f, 0.f, 0.f, 0.f, 0.f, 0.f, 0.f, 0.f};
#pragma unroll
    for (int kc = 0; kc < 16; ++kc) {
        float4 a = ws[kc];
        float4 b = wf[kc];
#pragma unroll
        for (int m = 0; m < 8; ++m) {
            float h0 = bcast_f(hreg[m], 4 * kc + 0);
            float h1 = bcast_f(hreg[m], 4 * kc + 1);
            float h2 = bcast_f(hreg[m], 4 * kc + 2);
            float h3 = bcast_f(hreg[m], 4 * kc + 3);
            accs[m] += h0 * a.x + h1 * a.y + h2 * a.z + h3 * a.w;
            accf[m] += h0 * b.x + h1 * b.y + h2 * b.z + h3 * b.w;
        }
    }
    float a_s = attn[lane], a_d = attn[DH + lane];
#pragma unroll
    for (int m = 0; m < 8; ++m) {
        int n = n0 + m;
        if (n < N_NODES) {
            zh[n * DH + lane] = __float2half(accf[m]);
            hs[n * DH + lane] = accs[m];
            float ps = accf[m] * a_s;
            float pd = accf[m] * a_d;
            for (int off = 32; off; off >>= 1) {
                ps += __shfl_down(ps, off);
                pd += __shfl_down(pd, off);
            }
            if (lane == 0) { s_src[n] = ps; s_dst[n] = pd; }
        }
    }
}

// ---------------- fused edge softmax + aggregation (gather, no atomics) ----------------
// one wave per destination node; packed CSR word; 16-wide gather batches
__global__ void k_agg(const int* __restrict__ row_off, const unsigned* __restrict__ csr,
                      const float* __restrict__ s_src, const float* __restrict__ s_dstA,
                      const float* __restrict__ consts, int layer,
                      const __half* __restrict__ zh, const float* __restrict__ hsb,
                      float* __restrict__ h) {
    int wave = threadIdx.x >> 6, lane = threadIdx.x & 63;
    int n = blockIdx.x * 4 + wave;
    if (n >= N_NODES) return;
    int rs = row_off[n], re = row_off[n + 1];
    int deg = re - rs;
    float hold = h[n * DH + lane];
    if (deg == 0) {
        h[n * DH + lane] = hold + fmaxf(hold, 0.f);
        return;
    }
    float c1 = consts[layer * 2 + 0];
    float c0 = consts[layer * 2 + 1];
    float sd = s_dstA[n];
    float hsv = hsb[n * DH + lane];

    // phase 1: per-edge logits (chunk 0 cached in regs), wave max
    float e0 = -1e30f;
    int s0 = 0;
    if (lane < deg) {
        unsigned w = csr[rs + lane];
        s0 = (int)(w & 0x1FFFFu);
        float ew = (float)(w >> 17) * (1.f / 32768.f);
        float e = s_src[s0] + sd + ew * c1 + c0;
        e0 = (e > 0.f) ? e : NEG_SLOPE * e;
    }
    float m = e0;
    for (int base = 64; base < deg; base += 64) {
        if (base + lane < deg) {
            unsigned w = csr[rs + base + lane];
            int si = (int)(w & 0x1FFFFu);
            float ew = (float)(w >> 17) * (1.f / 32768.f);
            float e = s_src[si] + sd + ew * c1 + c0;
            e = (e > 0.f) ? e : NEG_SLOPE * e;
            m = fmaxf(m, e);
        }
    }
    for (int off = 32; off; off >>= 1) m = fmaxf(m, __shfl_xor(m, off));

    // phase 2+3: exp, denom, accumulate ex * z[src]; batches of 16 gathers
    int cnt = (deg < 64) ? deg : 64;
    float ex = (lane < cnt) ? __expf(e0 - m) : 0.f; // inactive lanes: ex=0, s0=0
    float ssum = ex;
    float acc = 0.f;
    int nb = (cnt + 15) >> 4;
    for (int B = 0; B < nb; ++B) {
        int b0 = B << 4;
        float zv[16];
#pragma unroll
        for (int t = 0; t < 16; ++t) {
            int sb = __builtin_amdgcn_readlane(s0, b0 + t);
            zv[t] = __half2float(zh[(sb << 6) + lane]);
        }
#pragma unroll
        for (int t = 0; t < 16; ++t) {
            float exb = bcast_f(ex, b0 + t);
            acc += exb * zv[t];
        }
    }
    for (int base = 64; base < deg; base += 64) { // rare tail (deg > 64)
        float ext = 0.f;
        int si = 0;
        if (base + lane < deg) {
            unsigned w = csr[rs + base + lane];
            si = (int)(w & 0x1FFFFu);
            float ew = (float)(w >> 17) * (1.f / 32768.f);
            float e = s_src[si] + sd + ew * c1 + c0;
            e = (e > 0.f) ? e : NEG_SLOPE * e;
            ext = __expf(e - m);
        }
        ssum += ext;
        int cnt2 = deg - base;
        if (cnt2 > 64) cnt2 = 64;
        for (int b = 0; b < cnt2; ++b) {
            float exb = bcast_f(ext, b);
            int sb = __builtin_amdgcn_readlane(si, b);
            acc += exb * __half2float(zh[(sb << 6) + lane]);
        }
    }
    for (int off = 32; off; off >>= 1) ssum += __shfl_xor(ssum, off);

    float hmid = hsv + acc / ssum;
    h[n * DH + lane] = hold + fmaxf(hmid, 0.f);
}

__global__ void k_final(const float* __restrict__ h, const float* __restrict__ W,
                        const float* __restrict__ b, float* __restrict__ y) {
    int idx = blockIdx.x * blockDim.x + threadIdx.x;
    if (idx >= N_NODES * DOUT) return;
    int n = idx / DOUT, o = idx % DOUT;
    const float4* hrow = (const float4*)(h + n * DH);
    const float4* wrow = (const float4*)(W + o * DH);
    float acc = b[o];
#pragma unroll
    for (int k = 0; k < DH / 4; ++k) {
        float4 hv = hrow[k], wv = wrow[k];
        acc += hv.x * wv.x + hv.y * wv.y + hv.z * wv.z + hv.w * wv.w;
    }
    y[idx] = acc;
}

extern "C" void kernel_launch(void* const* d_in, const int* in_sizes, int n_in,
                              void* d_out, int out_size, void* d_ws, size_t ws_size,
                              hipStream_t stream) {
    const float* feats   = (const float*)d_in[0];
    const float* e_w     = (const float*)d_in[1];
    const int*   src     = (const int*)d_in[4];
    const int*   dst     = (const int*)d_in[5];
    const float* emb_h_W = (const float*)d_in[6];
    const float* emb_h_b = (const float*)d_in[7];
    const float* emb_e_W = (const float*)d_in[8];
    const float* emb_e_b = (const float*)d_in[9];
    const float* Wself[2] = {(const float*)d_in[10], (const float*)d_in[13]};
    const float* Wfunc[2] = {(const float*)d_in[11], (const float*)d_in[14]};
    const float* attn[2]  = {(const float*)d_in[12], (const float*)d_in[15]};
    const float* lin1_W  = (const float*)d_in[16];
    const float* lin1_b  = (const float*)d_in[17];
    float* y = (float*)d_out;

    char* ws = (char*)d_ws;
    size_t off = 0;
    auto alloc = [&](size_t bytes) {
        void* p = ws + off;
        off += (bytes + 255) & ~(size_t)255;
        return p;
    };
    float*    h       = (float*)alloc((size_t)N_NODES * DH * 4);
    __half*   zh      = (__half*)alloc((size_t)N_NODES * DH * 2);
    float*    hs      = (float*)alloc((size_t)N_NODES * DH * 4);
    unsigned* csr     = (unsigned*)alloc((size_t)N_EDGES * 4);
    unsigned* tmp     = (unsigned*)alloc((size_t)N_EDGES * 4);
    float*    s_src   = (float*)alloc((size_t)N_NODES * 4);
    float*    s_dst   = (float*)alloc((size_t)N_NODES * 4);
    int*      row_off = (int*)alloc((size_t)(N_NODES + 1) * 4);
    int*      cursor  = (int*)alloc((size_t)N_NODES * 4);
    int*      deg     = (int*)alloc((size_t)N_NODES * 4);
    int*      part    = (int*)alloc(256 * 4);
    float*    consts  = (float*)alloc(4 * 4);

    const int nblk_scan = (N_NODES + SCAN_BLK - 1) / SCAN_BLK; // 49

    k_consts<<<1, 64, 0, stream>>>(emb_e_W, emb_e_b, attn[0], attn[1], consts);

    const int nNode = N_NODES * DH;
    k_embed<<<(nNode + 255) / 256, 256, 0, stream>>>(feats, emb_h_W, emb_h_b, h);

    // CSR build (graph identical for both layers)
    hipMemsetAsync(deg, 0, (size_t)N_NODES * 4, stream);
    k_pack<<<(N_EDGES + 255) / 256, 256, 0, stream>>>(src, e_w, tmp);
    k_hist<<<NCHUNK * 8, 256, 0, stream>>>(dst, deg);
    k_scan1<<<nblk_scan, 256, 0, stream>>>(deg, row_off, part);
    k_scan2<<<1, 64, 0, stream>>>(part, nblk_scan);
    k_scan3<<<(N_NODES + 255) / 256, 256, 0, stream>>>(row_off, part, cursor);
    k_scatter<<<NCHUNK * 8, 256, 0, stream>>>(dst, tmp, cursor, csr);

    for (int l = 0; l < 2; ++l) {
        k_node<<<(N_NODES + 31) / 32, 256, 0, stream>>>(h, Wself[l], Wfunc[l], attn[l],
                                                        zh, hs, s_src, s_dst);
        k_agg<<<(N_NODES + 3) / 4, 256, 0, stream>>>(row_off, csr,
                                                     s_src, s_dst, consts, l, zh, hs, h);
    }

    k_final<<<(N_NODES * DOUT + 255) / 256, 256, 0, stream>>>(h, lin1_W, lin1_b, y);
}

// Round 5
// 481.528 us; speedup vs baseline: 4.2153x; 1.3141x over previous
//
#include <hip/hip_runtime.h>
#include <hip/hip_fp16.h>

#define N_NODES 100000
#define N_EDGES 1600000
#define DIN 24
#define DH 64
#define DOUT 12
#define NEG_SLOPE 0.01f
#define SCAN_BLK 2048   // elements per scan block (256 threads x 8)
#define SLICE 12500     // N_NODES / 8 : dst-space slice per XCD group
#define NCHUNK 128      // edge chunks for sliced kernels
#define ECH ((N_EDGES + NCHUNK - 1) / NCHUNK)  // 12500 edges per chunk
#define LDSW 72         // LDS row stride in halves: 144 B (16B-aligned, 2-way banks = free)

typedef _Float16 half8_t __attribute__((ext_vector_type(8)));
typedef float floatx4 __attribute__((ext_vector_type(4)));

__device__ __forceinline__ float bcast_f(float v, int srclane) {
    return __uint_as_float(__builtin_amdgcn_readlane(__float_as_uint(v), srclane));
}

// consts[0..3] = {c1_l1, c0_l1, c1_l2, c0_l2} : edge_term = e_w*c1 + c0
__global__ void k_consts(const float* __restrict__ emb_e_W, const float* __restrict__ emb_e_b,
                         const float* __restrict__ attn1, const float* __restrict__ attn2,
                         float* __restrict__ consts) {
    int lane = threadIdx.x;
    float w = emb_e_W[lane];
    float b = emb_e_b[lane];
    float a1 = attn1[2 * DH + lane];
    float a2 = attn2[2 * DH + lane];
    float c11 = w * a1, c01 = b * a1, c12 = w * a2, c02 = b * a2;
    for (int off = 32; off; off >>= 1) {
        c11 += __shfl_down(c11, off);
        c01 += __shfl_down(c01, off);
        c12 += __shfl_down(c12, off);
        c02 += __shfl_down(c02, off);
    }
    if (lane == 0) {
        consts[0] = c11; consts[1] = c01; consts[2] = c12; consts[3] = c02;
    }
}

__global__ void k_embed(const float* __restrict__ feats, const float* __restrict__ W,
                        const float* __restrict__ b, float* __restrict__ h) {
    int idx = blockIdx.x * blockDim.x + threadIdx.x;
    if (idx >= N_NODES * DH) return;
    int n = idx >> 6, o = idx & 63;
    const float* f = feats + n * DIN;
    const float* w = W + o * DIN;
    float acc = b[o];
#pragma unroll
    for (int k = 0; k < DIN; ++k) acc += f[k] * w[k];
    h[idx] = acc;
}

// ---------------- CSR build ----------------
// pack (src 17b | e_w q15 << 17) — one 4B payload per edge
__global__ void k_pack(const int* __restrict__ src, const float* __restrict__ e_w,
                       unsigned* __restrict__ tmp) {
    int i = blockIdx.x * blockDim.x + threadIdx.x;
    if (i >= N_EDGES) return;
    unsigned q = (unsigned)(e_w[i] * 32768.f);
    if (q > 32767u) q = 32767u;
    tmp[i] = (unsigned)src[i] | (q << 17);
}

// XCD-sliced histogram: group g = blockIdx&7 handles dst in [g*SLICE,(g+1)*SLICE)
__global__ void k_hist(const int* __restrict__ dst, int* __restrict__ deg) {
    int g = blockIdx.x & 7;
    int start = (blockIdx.x >> 3) * ECH;
    int end = start + ECH;
    if (end > N_EDGES) end = N_EDGES;
    for (int i = start + threadIdx.x; i < end; i += 256) {
        int d = dst[i];
        if ((unsigned)d / SLICE == (unsigned)g) atomicAdd(deg + d, 1);
    }
}

__global__ void k_scan1(const int* __restrict__ deg, int* __restrict__ row_off,
                        int* __restrict__ part) {
    __shared__ int lds[256];
    int t = threadIdx.x;
    int base = blockIdx.x * SCAN_BLK + t * 8;
    int v[8];
    int s = 0;
#pragma unroll
    for (int i = 0; i < 8; ++i) {
        int idx = base + i;
        v[i] = (idx < N_NODES) ? deg[idx] : 0;
        s += v[i];
    }
    lds[t] = s;
    __syncthreads();
    for (int off = 1; off < 256; off <<= 1) {
        int y = (t >= off) ? lds[t - off] : 0;
        __syncthreads();
        lds[t] += y;
        __syncthreads();
    }
    int run = lds[t] - s;
#pragma unroll
    for (int i = 0; i < 8; ++i) {
        int idx = base + i;
        if (idx < N_NODES) row_off[idx] = run;
        run += v[i];
    }
    if (t == 255) part[blockIdx.x] = lds[255];
}

__global__ void k_scan2(int* __restrict__ part, int nblk) {
    int lane = threadIdx.x;
    int orig = (lane < nblk) ? part[lane] : 0;
    int v = orig;
    for (int off = 1; off < 64; off <<= 1) {
        int y = __shfl_up(v, off);
        if (lane >= off) v += y;
    }
    if (lane < nblk) part[lane] = v - orig;
}

__global__ void k_scan3(int* __restrict__ row_off, const int* __restrict__ part,
                        int* __restrict__ cursor) {
    int i = blockIdx.x * blockDim.x + threadIdx.x;
    if (i >= N_NODES) return;
    int v = row_off[i] + part[i / SCAN_BLK];
    row_off[i] = v;
    cursor[i] = v;
    if (i == 0) row_off[N_NODES] = N_EDGES;
}

// XCD-sliced scatter
__global__ void k_scatter(const int* __restrict__ dst, const unsigned* __restrict__ tmp,
                          int* __restrict__ cursor, unsigned* __restrict__ csr) {
    int g = blockIdx.x & 7;
    int start = (blockIdx.x >> 3) * ECH;
    int end = start + ECH;
    if (end > N_EDGES) end = N_EDGES;
    for (int i = start + threadIdx.x; i < end; i += 256) {
        int d = dst[i];
        if ((unsigned)d / SLICE == (unsigned)g) {
            int pos = atomicAdd(cursor + d, 1);
            csr[pos] = tmp[i];
        }
    }
}

// ---------------- per-layer node GEMM via MFMA ----------------
// Wave = 16 nodes (M=16); N=64 in 4 tiles; K=64 in 2 steps of 32.
// A frag: A[m=lane&15][k=quad*8+j]; B frag ([N][K] = W layout): W[16t+lm][ks*32+quad*8+j]
// D: col(n)=lane&15, row(m)=quad*4+reg.  Weights staged fp16 in LDS (stride 72 halves).
__global__ void __launch_bounds__(256, 4)
k_node(const float* __restrict__ h,
       const float* __restrict__ Wself, const float* __restrict__ Wfunc,
       const float* __restrict__ attn,
       __half* __restrict__ zh, float* __restrict__ hs,
       float* __restrict__ s_src, float* __restrict__ s_dst) {
    __shared__ _Float16 lds[2 * 64 * LDSW];
    int tid = threadIdx.x;
    for (int idx = tid; idx < 2 * 64 * 64; idx += 256) {
        int mat = idx >> 12, rem = idx & 4095;
        int o = rem >> 6, k = rem & 63;
        float v = mat ? Wfunc[rem] : Wself[rem];
        lds[(mat * 64 + o) * LDSW + k] = (_Float16)v;
    }
    __syncthreads();

    int wave = tid >> 6, lane = tid & 63;
    int n0 = (blockIdx.x * 4 + wave) * 16;
    if (n0 >= N_NODES) return;  // 100000 % 16 == 0: in-range waves are fully valid
    int quad = lane >> 4, lm = lane & 15;

    // A fragments (2 k-steps) from fp32 h
    half8_t afrag[2];
    {
        const float4* hrow = (const float4*)(h + (size_t)(n0 + lm) * DH);
#pragma unroll
        for (int ks = 0; ks < 2; ++ks) {
            float4 p0 = hrow[ks * 8 + quad * 2];
            float4 p1 = hrow[ks * 8 + quad * 2 + 1];
            half8_t a;
            a[0] = (_Float16)p0.x; a[1] = (_Float16)p0.y;
            a[2] = (_Float16)p0.z; a[3] = (_Float16)p0.w;
            a[4] = (_Float16)p1.x; a[5] = (_Float16)p1.y;
            a[6] = (_Float16)p1.z; a[7] = (_Float16)p1.w;
            afrag[ks] = a;
        }
    }

    floatx4 accS[4], accF[4];
#pragma unroll
    for (int t = 0; t < 4; ++t) { accS[t] = (floatx4)0.f; accF[t] = (floatx4)0.f; }

    const _Float16* bS = lds;
    const _Float16* bF = lds + 64 * LDSW;
#pragma unroll
    for (int t = 0; t < 4; ++t) {
        int o = t * 16 + lm;
#pragma unroll
        for (int ks = 0; ks < 2; ++ks) {
            int hoff = o * LDSW + ks * 32 + quad * 8;
            half8_t b1 = *(const half8_t*)(bS + hoff);
            half8_t b2 = *(const half8_t*)(bF + hoff);
            accS[t] = __builtin_amdgcn_mfma_f32_16x16x32_f16(afrag[ks], b1, accS[t], 0, 0, 0);
            accF[t] = __builtin_amdgcn_mfma_f32_16x16x32_f16(afrag[ks], b2, accF[t], 0, 0, 0);
        }
    }

    // epilogue: stores + attention dots
    float asv[4], adv[4];
#pragma unroll
    for (int t = 0; t < 4; ++t) {
        asv[t] = attn[t * 16 + lm];
        adv[t] = attn[DH + t * 16 + lm];
    }
    float ps[4] = {0.f, 0.f, 0.f, 0.f}, pd[4] = {0.f, 0.f, 0.f, 0.f};
#pragma unroll
    for (int t = 0; t < 4; ++t) {
#pragma unroll
        for (int r = 0; r < 4; ++r) {
            int node = n0 + quad * 4 + r;
            float zv = accF[t][r];
            zh[(size_t)node * DH + t * 16 + lm] = __float2half(zv);
            hs[(size_t)node * DH + t * 16 + lm] = accS[t][r];
            ps[r] += zv * asv[t];
            pd[r] += zv * adv[t];
        }
    }
#pragma unroll
    for (int r = 0; r < 4; ++r) {
        float p1 = ps[r], p2 = pd[r];
        for (int off = 8; off; off >>= 1) {  // reduce across the 16 lanes of the quad
            p1 += __shfl_xor(p1, off);
            p2 += __shfl_xor(p2, off);
        }
        if (lm == 0) {
            s_src[n0 + quad * 4 + r] = p1;
            s_dst[n0 + quad * 4 + r] = p2;
        }
    }
}

// ---------------- fused edge softmax + aggregation (gather, no atomics) ----------------
__global__ void k_agg(const int* __restrict__ row_off, const unsigned* __restrict__ csr,
                      const float* __restrict__ s_src, const float* __restrict__ s_dstA,
                      const float* __restrict__ consts, int layer,
                      const __half* __restrict__ zh, const float* __restrict__ hsb,
                      float* __restrict__ h) {
    int wave = threadIdx.x >> 6, lane = threadIdx.x & 63;
    int n = blockIdx.x * 4 + wave;
    if (n >= N_NODES) return;
    int rs = row_off[n], re = row_off[n + 1];
    int deg = re - rs;
    float hold = h[n * DH + lane];
    if (deg == 0) {
        h[n * DH + lane] = hold + fmaxf(hold, 0.f);
        return;
    }
    float c1 = consts[layer * 2 + 0];
    float c0 = consts[layer * 2 + 1];
    float sd = s_dstA[n];
    float hsv = hsb[n * DH + lane];

    float e0 = -1e30f;
    int s0 = 0;
    if (lane < deg) {
        unsigned w = csr[rs + lane];
        s0 = (int)(w & 0x1FFFFu);
        float ew = (float)(w >> 17) * (1.f / 32768.f);
        float e = s_src[s0] + sd + ew * c1 + c0;
        e0 = (e > 0.f) ? e : NEG_SLOPE * e;
    }
    float m = e0;
    for (int base = 64; base < deg; base += 64) {
        if (base + lane < deg) {
            unsigned w = csr[rs + base + lane];
            int si = (int)(w & 0x1FFFFu);
            float ew = (float)(w >> 17) * (1.f / 32768.f);
            float e = s_src[si] + sd + ew * c1 + c0;
            e = (e > 0.f) ? e : NEG_SLOPE * e;
            m = fmaxf(m, e);
        }
    }
    for (int off = 32; off; off >>= 1) m = fmaxf(m, __shfl_xor(m, off));

    int cnt = (deg < 64) ? deg : 64;
    float ex = (lane < cnt) ? __expf(e0 - m) : 0.f;
    float ssum = ex;
    float acc = 0.f;
    int nb = (cnt + 15) >> 4;
    for (int B = 0; B < nb; ++B) {
        int b0 = B << 4;
        float zv[16];
#pragma unroll
        for (int t = 0; t < 16; ++t) {
            int sb = __builtin_amdgcn_readlane(s0, b0 + t);
            zv[t] = __half2float(zh[(sb << 6) + lane]);
        }
#pragma unroll
        for (int t = 0; t < 16; ++t) {
            float exb = bcast_f(ex, b0 + t);
            acc += exb * zv[t];
        }
    }
    for (int base = 64; base < deg; base += 64) {
        float ext = 0.f;
        int si = 0;
        if (base + lane < deg) {
            unsigned w = csr[rs + base + lane];
            si = (int)(w & 0x1FFFFu);
            float ew = (float)(w >> 17) * (1.f / 32768.f);
            float e = s_src[si] + sd + ew * c1 + c0;
            e = (e > 0.f) ? e : NEG_SLOPE * e;
            ext = __expf(e - m);
        }
        ssum += ext;
        int cnt2 = deg - base;
        if (cnt2 > 64) cnt2 = 64;
        for (int b = 0; b < cnt2; ++b) {
            float exb = bcast_f(ext, b);
            int sb = __builtin_amdgcn_readlane(si, b);
            acc += exb * __half2float(zh[(sb << 6) + lane]);
        }
    }
    for (int off = 32; off; off >>= 1) ssum += __shfl_xor(ssum, off);

    float hmid = hsv + acc / ssum;
    h[n * DH + lane] = hold + fmaxf(hmid, 0.f);
}

__global__ void k_final(const float* __restrict__ h, const float* __restrict__ W,
                        const float* __restrict__ b, float* __restrict__ y) {
    int idx = blockIdx.x * blockDim.x + threadIdx.x;
    if (idx >= N_NODES * DOUT) return;
    int n = idx / DOUT, o = idx % DOUT;
    const float4* hrow = (const float4*)(h + n * DH);
    const float4* wrow = (const float4*)(W + o * DH);
    float acc = b[o];
#pragma unroll
    for (int k = 0; k < DH / 4; ++k) {
        float4 hv = hrow[k], wv = wrow[k];
        acc += hv.x * wv.x + hv.y * wv.y + hv.z * wv.z + hv.w * wv.w;
    }
    y[idx] = acc;
}

extern "C" void kernel_launch(void* const* d_in, const int* in_sizes, int n_in,
                              void* d_out, int out_size, void* d_ws, size_t ws_size,
                              hipStream_t stream) {
    const float* feats   = (const float*)d_in[0];
    const float* e_w     = (const float*)d_in[1];
    const int*   src     = (const int*)d_in[4];
    const int*   dst     = (const int*)d_in[5];
    const float* emb_h_W = (const float*)d_in[6];
    const float* emb_h_b = (const float*)d_in[7];
    const float* emb_e_W = (const float*)d_in[8];
    const float* emb_e_b = (const float*)d_in[9];
    const float* Wself[2] = {(const float*)d_in[10], (const float*)d_in[13]};
    const float* Wfunc[2] = {(const float*)d_in[11], (const float*)d_in[14]};
    const float* attn[2]  = {(const float*)d_in[12], (const float*)d_in[15]};
    const float* lin1_W  = (const float*)d_in[16];
    const float* lin1_b  = (const float*)d_in[17];
    float* y = (float*)d_out;

    char* ws = (char*)d_ws;
    size_t off = 0;
    auto alloc = [&](size_t bytes) {
        void* p = ws + off;
        off += (bytes + 255) & ~(size_t)255;
        return p;
    };
    float*    h       = (float*)alloc((size_t)N_NODES * DH * 4);
    __half*   zh      = (__half*)alloc((size_t)N_NODES * DH * 2);
    float*    hs      = (float*)alloc((size_t)N_NODES * DH * 4);
    unsigned* csr     = (unsigned*)alloc((size_t)N_EDGES * 4);
    unsigned* tmp     = (unsigned*)alloc((size_t)N_EDGES * 4);
    float*    s_src   = (float*)alloc((size_t)N_NODES * 4);
    float*    s_dst   = (float*)alloc((size_t)N_NODES * 4);
    int*      row_off = (int*)alloc((size_t)(N_NODES + 1) * 4);
    int*      cursor  = (int*)alloc((size_t)N_NODES * 4);
    int*      deg     = (int*)alloc((size_t)N_NODES * 4);
    int*      part    = (int*)alloc(256 * 4);
    float*    consts  = (float*)alloc(4 * 4);

    const int nblk_scan = (N_NODES + SCAN_BLK - 1) / SCAN_BLK; // 49

    k_consts<<<1, 64, 0, stream>>>(emb_e_W, emb_e_b, attn[0], attn[1], consts);

    const int nNode = N_NODES * DH;
    k_embed<<<(nNode + 255) / 256, 256, 0, stream>>>(feats, emb_h_W, emb_h_b, h);

    hipMemsetAsync(deg, 0, (size_t)N_NODES * 4, stream);
    k_pack<<<(N_EDGES + 255) / 256, 256, 0, stream>>>(src, e_w, tmp);
    k_hist<<<NCHUNK * 8, 256, 0, stream>>>(dst, deg);
    k_scan1<<<nblk_scan, 256, 0, stream>>>(deg, row_off, part);
    k_scan2<<<1, 64, 0, stream>>>(part, nblk_scan);
    k_scan3<<<(N_NODES + 255) / 256, 256, 0, stream>>>(row_off, part, cursor);
    k_scatter<<<NCHUNK * 8, 256, 0, stream>>>(dst, tmp, cursor, csr);

    for (int l = 0; l < 2; ++l) {
        // MFMA node GEMM: 16 nodes/wave, 4 waves/block -> 64 nodes/block
        k_node<<<(N_NODES + 63) / 64, 256, 0, stream>>>(h, Wself[l], Wfunc[l], attn[l],
                                                        zh, hs, s_src, s_dst);
        k_agg<<<(N_NODES + 3) / 4, 256, 0, stream>>>(row_off, csr,
                                                     s_src, s_dst, consts, l, zh, hs, h);
    }

    k_final<<<(N_NODES * DOUT + 255) / 256, 256, 0, stream>>>(h, lin1_W, lin1_b, y);
}